// Round 8
// baseline (2188.629 us; speedup 1.0000x reference)
//
#include <hip/hip_runtime.h>
#include <float.h>

#define B_ 16
#define N_ 4096
#define M_ 1024
#define K_ 32
#define FEAT_ 64
#define H_ 128
#define GEO_IN_ 160
#define GEO_MID_ 130
#define FEAT_IN_ 2048

typedef unsigned short u16t;

// ---- wave64 reductions in the VALU pipe (DPP), identity-preserving ----
#define DPP_STEP_MAX(ctrl) \
  t=(unsigned)__builtin_amdgcn_update_dpp((int)v,(int)v,(ctrl),0xf,0xf,false); \
  v=(t>v)?t:v;
#define DPP_STEP_MIN(ctrl) \
  t=(unsigned)__builtin_amdgcn_update_dpp((int)v,(int)v,(ctrl),0xf,0xf,false); \
  v=(t<v)?t:v;

__device__ __forceinline__ unsigned wave_max_u32(unsigned v){
  unsigned t;
  DPP_STEP_MAX(0x111) DPP_STEP_MAX(0x112) DPP_STEP_MAX(0x114) DPP_STEP_MAX(0x118)
  DPP_STEP_MAX(0x142) DPP_STEP_MAX(0x143)
  return (unsigned)__builtin_amdgcn_readlane((int)v,63);
}
__device__ __forceinline__ unsigned wave_min_u32(unsigned v){
  unsigned t;
  DPP_STEP_MIN(0x111) DPP_STEP_MIN(0x112) DPP_STEP_MIN(0x114) DPP_STEP_MIN(0x118)
  DPP_STEP_MIN(0x142) DPP_STEP_MIN(0x143)
  return (unsigned)__builtin_amdgcn_readlane((int)v,63);
}

// ---------------------------------------------------------------- FPS
// One block (256 thr = 4 waves) per batch, 16 pts/thread in registers.
// NO __syncthreads in the step loop: cross-wave exchange via seqlock-style
// LDS records (key,coords,then tag=t; consumer reads tags first). DS ops
// complete in order per wave => tag==t guarantees data freshness. Depth-2
// buffer is safe: publishing t+2 requires all waves consumed t.
// Semantics: max dist, tie -> smallest index; no FMA contraction in distance.
__global__ __launch_bounds__(256) void fps_kernel(
    const float* __restrict__ xyz, float* __restrict__ outc)
{
  const int b = blockIdx.x, tid = threadIdx.x;
  const int wv = tid >> 6;
  const float* xb = xyz + (size_t)b * (N_*3);
  __shared__ unsigned long long skey[2][4];
  __shared__ float sx[2][4], sy[2][4], sz[2][4];
  __shared__ unsigned stag[2][4];
  __shared__ float clist[M_][3];          // 12 KB
  if (tid<8) stag[tid>>2][tid&3]=0u;      // t starts at 1; 0 never matches
  float px[16], py[16], pz[16], dd[16];
#pragma unroll
  for (int j=0;j<16;j++){
    int i = tid + 256*j;
    px[j]=xb[i*3]; py[j]=xb[i*3+1]; pz[j]=xb[i*3+2];
    dd[j]=FLT_MAX;
  }
  float lx=xb[0], ly=xb[1], lz=xb[2];
  if (tid==0){ clist[0][0]=lx; clist[0][1]=ly; clist[0][2]=lz; }
  __syncthreads();                        // stag init visible
  for (int t=1;t<M_;t++){
    // dist update (independent per j) + contiguous-pair tree argmax
    float td[16]; int ti[16];
#pragma unroll
    for (int j=0;j<16;j++){
      float dx=__fsub_rn(px[j],lx), dy=__fsub_rn(py[j],ly), dz=__fsub_rn(pz[j],lz);
      float d=__fadd_rn(__fadd_rn(__fmul_rn(dx,dx),__fmul_rn(dy,dy)),__fmul_rn(dz,dz));
      d=fminf(dd[j],d); dd[j]=d;
      td[j]=d; ti[j]=tid+256*j;           // ti ascending in j
    }
#pragma unroll
    for (int s=1;s<16;s<<=1)
#pragma unroll
      for (int j=0;j<16;j+=2*s)
        if (td[j+s]>td[j]){ td[j]=td[j+s]; ti[j]=ti[j+s]; }  // strict > keeps leftmost max
    float bd=td[0]; int bi=ti[0];
    unsigned db=__float_as_uint(bd);          // bd>=0 => bits order-monotone
    unsigned smax=wave_max_u32(db);
    unsigned cand=(db==smax)?(unsigned)bi:0x7FFFFFFFu;
    unsigned sbi=wave_min_u32(cand);
    int p=t&1;
    if ((unsigned)tid==(sbi&255u)){           // owner lane is inside this wave
      int oj=(int)(sbi>>8);
      *(volatile unsigned long long*)&skey[p][wv]=
          ((unsigned long long)smax<<32)|(unsigned)(0xFFFFFFFFu-sbi);
      *(volatile float*)&sx[p][wv]=px[oj];
      *(volatile float*)&sy[p][wv]=py[oj];
      *(volatile float*)&sz[p][wv]=pz[oj];
      *(volatile unsigned*)&stag[p][wv]=(unsigned)t;   // tag LAST
    }
    unsigned long long K0,K1,K2,K3;
    float X0,Y0,Z0,X1,Y1,Z1,X2,Y2,Z2,X3,Y3,Z3;
    for(;;){
      unsigned t0=*(volatile unsigned*)&stag[p][0];    // tags read FIRST
      unsigned t1=*(volatile unsigned*)&stag[p][1];
      unsigned t2=*(volatile unsigned*)&stag[p][2];
      unsigned t3=*(volatile unsigned*)&stag[p][3];
      K0=*(volatile unsigned long long*)&skey[p][0];
      K1=*(volatile unsigned long long*)&skey[p][1];
      K2=*(volatile unsigned long long*)&skey[p][2];
      K3=*(volatile unsigned long long*)&skey[p][3];
      X0=*(volatile float*)&sx[p][0]; Y0=*(volatile float*)&sy[p][0]; Z0=*(volatile float*)&sz[p][0];
      X1=*(volatile float*)&sx[p][1]; Y1=*(volatile float*)&sy[p][1]; Z1=*(volatile float*)&sz[p][1];
      X2=*(volatile float*)&sx[p][2]; Y2=*(volatile float*)&sy[p][2]; Z2=*(volatile float*)&sz[p][2];
      X3=*(volatile float*)&sx[p][3]; Y3=*(volatile float*)&sy[p][3]; Z3=*(volatile float*)&sz[p][3];
      unsigned tt=(unsigned)t;
      if ((((t0^tt)|(t1^tt))|((t2^tt)|(t3^tt)))==0u) break;
    }
    // merge 4 candidates: higher key wins (keys strictly distinct)
    if (K1>K0){ K0=K1; X0=X1; Y0=Y1; Z0=Z1; }
    if (K3>K2){ K2=K3; X2=X3; Y2=Y3; Z2=Z3; }
    if (K2>K0){ K0=K2; X0=X2; Y0=Y2; Z0=Z2; }
    lx=X0; ly=Y0; lz=Z0;
    if (tid==0){ clist[t][0]=lx; clist[t][1]=ly; clist[t][2]=lz; }
  }
  __syncthreads();
  for (int e=tid; e<M_; e+=256){
    size_t cb=((size_t)b*M_+(size_t)e)*3;
    outc[cb]=clist[e][0]; outc[cb+1]=clist[e][1]; outc[cb+2]=clist[e][2];
  }
}

// ---------------------------------------------------------------- KNN
// One wave per centroid. 64 dists/lane. Selection via 2x u32 DPP (min dist,
// then min global idx among ties) == stable top_k. Owner lane keeps a top-2
// cache (lex (d,j) order, exactly matching a sequential first-min scan);
// full rescan (with popped mask) only when the cache empties.
__global__ __launch_bounds__(256) void knn_kernel(
    const float* __restrict__ xyz, const float* __restrict__ outc,
    u16t* __restrict__ gidx16)
{
  const int w = blockIdx.x*4 + (threadIdx.x>>6);
  const int lane = threadIdx.x & 63;
  const int b = w >> 10;
  const float* xb = xyz + (size_t)b*(N_*3);
  float cx=outc[(size_t)w*3], cy=outc[(size_t)w*3+1], cz=outc[(size_t)w*3+2];
  float c2=__fadd_rn(__fadd_rn(__fmul_rn(cx,cx),__fmul_rn(cy,cy)),__fmul_rn(cz,cz));
  float dl[64];
#pragma unroll
  for (int j=0;j<64;j++){
    int i = lane + 64*j;
    float xx=xb[i*3], xy=xb[i*3+1], xz=xb[i*3+2];
    float x2=__fadd_rn(__fadd_rn(__fmul_rn(xx,xx),__fmul_rn(xy,xy)),__fmul_rn(xz,xz));
    float dt=__fadd_rn(__fadd_rn(__fmul_rn(cx,xx),__fmul_rn(cy,xy)),__fmul_rn(cz,xz));
    dl[j]=__fsub_rn(__fadd_rn(c2,x2),__fmul_rn(2.f,dt));
  }
  // build top-2 (lex (d,j): strict < keeps earliest j)
  float m1=FLT_MAX,m2=FLT_MAX; int j1=64,j2=64;
#pragma unroll
  for (int j=0;j<64;j++){
    float d=dl[j];
    bool b1=(d<m1), b2=(d<m2);
    float nm2=b1?m1:(b2?d:m2); int nj2=b1?j1:(b2?j:j2);
    float nm1=b1?d:m1;         int nj1=b1?j:j1;
    m1=nm1;j1=nj1;m2=nm2;j2=nj2;
  }
  unsigned long long popped=0ull;
  const int wb = w*K_;
  for (int k=0;k<K_;k++){
    unsigned u=__float_as_uint(m1);
    u = (u&0x80000000u) ? ~u : (u|0x80000000u);   // order-preserving
    unsigned smin=wave_min_u32(u);
    unsigned cand=(u==smin)?(unsigned)(lane+64*j1):0xFFFFFFFFu;
    unsigned widx=wave_min_u32(cand);
    if (lane==0) gidx16[wb+k]=(u16t)widx;
    if ((widx & 63)==(unsigned)lane){
      popped |= (1ull<<j1);
      if (j2<64){ m1=m2; j1=j2; m2=FLT_MAX; j2=64; }
      else {
        m1=FLT_MAX; m2=FLT_MAX; j1=64; j2=64;
#pragma unroll
        for (int j=0;j<64;j++){
          float d=((popped>>j)&1ull)?FLT_MAX:dl[j];
          bool b1=(d<m1), b2=(d<m2);
          float nm2=b1?m1:(b2?d:m2); int nj2=b1?j1:(b2?j:j2);
          float nm1=b1?d:m1;         int nj1=b1?j:j1;
          m1=nm1;j1=nj1;m2=nm2;j2=nj2;
        }
      }
    }
  }
}

// ---------------------------------------------------------------- GEO fused (GEMM-style)
// (unchanged from round 7)
__global__ __launch_bounds__(256) void geo_kernel(
    const float* __restrict__ xyz, const float* __restrict__ outc,
    const u16t* __restrict__ gidx16, const float* __restrict__ W1,
    const float* __restrict__ Wout, float* __restrict__ xout)
{
  __shared__ float smem[160*33 + 64*128 + 32];
  float (*Es)[33]  = (float(*)[33])smem;
  float (*Hs)[33]  = (float(*)[33])smem;
  float (*Ws)[128] = (float(*)[128])(smem + 160*33);
  float* ssv = smem + 160*33 + 64*128;

  const int t=threadIdx.x;
  const int g0=blockIdx.x*32;
  for (int p=t; p<1024; p+=256){
    int g=p>>5, kk=p&31;
    int gg=g0+g, b=gg>>10;
    int idx=gidx16[gg*K_+kk];
    const float* pt = xyz + ((size_t)b*N_+(size_t)idx)*3;
    const float* cc = outc + (size_t)gg*3;
    float dx=__fsub_rn(pt[0],cc[0]);
    float dy=__fsub_rn(pt[1],cc[1]);
    float dz=__fsub_rn(pt[2],cc[2]);
    float sq=__fadd_rn(__fadd_rn(__fmul_rn(dx,dx),__fmul_rn(dy,dy)),__fmul_rn(dz,dz));
    int r=5*kk;
    Es[r][g]=dx; Es[r+1][g]=dy; Es[r+2][g]=dz;
    Es[r+3][g]=-1.f; Es[r+4][g]=__fmul_rn(-0.5f,sq);
  }
  const int gsub=t>>4, hsub=t&15, h0=hsub*8;
  const int hw=t>>1;
  float acc[2][8];
#pragma unroll
  for (int a=0;a<2;a++)
#pragma unroll
    for (int j=0;j<8;j++) acc[a][j]=0.f;
  __syncthreads();

  for (int c=0;c<3;c++){
    int i0=c*64;
    if (c<2){
      int fw0=(t&1)*32;
      const float* wr = W1 + (size_t)hw*GEO_IN_ + i0 + fw0;
      float4 wv[8];
#pragma unroll
      for (int e=0;e<8;e++) wv[e]=((const float4*)wr)[e];
#pragma unroll
      for (int e=0;e<8;e++){
        Ws[fw0+4*e+0][hw]=wv[e].x;
        Ws[fw0+4*e+1][hw]=wv[e].y;
        Ws[fw0+4*e+2][hw]=wv[e].z;
        Ws[fw0+4*e+3][hw]=wv[e].w;
      }
    } else {
      int fw0=(t&1)*16;
      const float* wr = W1 + (size_t)hw*GEO_IN_ + 128 + fw0;
      float4 wv[4];
#pragma unroll
      for (int e=0;e<4;e++) wv[e]=((const float4*)wr)[e];
#pragma unroll
      for (int e=0;e<4;e++){
        Ws[fw0+4*e+0][hw]=wv[e].x;
        Ws[fw0+4*e+1][hw]=wv[e].y;
        Ws[fw0+4*e+2][hw]=wv[e].z;
        Ws[fw0+4*e+3][hw]=wv[e].w;
      }
    }
    __syncthreads();
    int len=(c==2)?32:64;
    for (int k2=0;k2<len;k2++){
      float x0=Es[i0+k2][2*gsub], x1=Es[i0+k2][2*gsub+1];
      const float* wp=&Ws[k2][h0];
      float4 wa=*(const float4*)wp;
      float4 wb=*(const float4*)(wp+4);
      acc[0][0]=__builtin_fmaf(x0,wa.x,acc[0][0]);
      acc[0][1]=__builtin_fmaf(x0,wa.y,acc[0][1]);
      acc[0][2]=__builtin_fmaf(x0,wa.z,acc[0][2]);
      acc[0][3]=__builtin_fmaf(x0,wa.w,acc[0][3]);
      acc[0][4]=__builtin_fmaf(x0,wb.x,acc[0][4]);
      acc[0][5]=__builtin_fmaf(x0,wb.y,acc[0][5]);
      acc[0][6]=__builtin_fmaf(x0,wb.z,acc[0][6]);
      acc[0][7]=__builtin_fmaf(x0,wb.w,acc[0][7]);
      acc[1][0]=__builtin_fmaf(x1,wa.x,acc[1][0]);
      acc[1][1]=__builtin_fmaf(x1,wa.y,acc[1][1]);
      acc[1][2]=__builtin_fmaf(x1,wa.z,acc[1][2]);
      acc[1][3]=__builtin_fmaf(x1,wa.w,acc[1][3]);
      acc[1][4]=__builtin_fmaf(x1,wb.x,acc[1][4]);
      acc[1][5]=__builtin_fmaf(x1,wb.y,acc[1][5]);
      acc[1][6]=__builtin_fmaf(x1,wb.z,acc[1][6]);
      acc[1][7]=__builtin_fmaf(x1,wb.w,acc[1][7]);
    }
    __syncthreads();
  }
#pragma unroll
  for (int a=0;a<2;a++)
#pragma unroll
    for (int j=0;j<8;j++)
      Hs[h0+j][2*gsub+a]=acc[a][j];
  __syncthreads();
  if (t<32){
    float ss=0.f;
    for (int h=0;h<H_;h++){ float v=Hs[h][t]; ss=__builtin_fmaf(v,v,ss); }
    ssv[t]=__fmul_rn(-0.5f,ss);
  }
#pragma unroll
  for (int a=0;a<2;a++)
#pragma unroll
    for (int j=0;j<8;j++) acc[a][j]=0.f;
  for (int c=0;c<2;c++){
    int i0=c*64;
    int fw0=(t&1)*32;
    const float* wr = Wout + (size_t)hw*GEO_MID_ + i0 + fw0;
    float2 wv2[16];
#pragma unroll
    for (int e=0;e<16;e++) wv2[e]=((const float2*)wr)[e];
    __syncthreads();
#pragma unroll
    for (int e=0;e<16;e++){
      Ws[fw0+2*e+0][hw]=wv2[e].x;
      Ws[fw0+2*e+1][hw]=wv2[e].y;
    }
    __syncthreads();
    for (int k2=0;k2<64;k2++){
      float x0=Hs[i0+k2][2*gsub], x1=Hs[i0+k2][2*gsub+1];
      const float* wp=&Ws[k2][h0];
      float4 wa=*(const float4*)wp;
      float4 wb=*(const float4*)(wp+4);
      acc[0][0]=__builtin_fmaf(x0,wa.x,acc[0][0]);
      acc[0][1]=__builtin_fmaf(x0,wa.y,acc[0][1]);
      acc[0][2]=__builtin_fmaf(x0,wa.z,acc[0][2]);
      acc[0][3]=__builtin_fmaf(x0,wa.w,acc[0][3]);
      acc[0][4]=__builtin_fmaf(x0,wb.x,acc[0][4]);
      acc[0][5]=__builtin_fmaf(x0,wb.y,acc[0][5]);
      acc[0][6]=__builtin_fmaf(x0,wb.z,acc[0][6]);
      acc[0][7]=__builtin_fmaf(x0,wb.w,acc[0][7]);
      acc[1][0]=__builtin_fmaf(x1,wa.x,acc[1][0]);
      acc[1][1]=__builtin_fmaf(x1,wa.y,acc[1][1]);
      acc[1][2]=__builtin_fmaf(x1,wa.z,acc[1][2]);
      acc[1][3]=__builtin_fmaf(x1,wa.w,acc[1][3]);
      acc[1][4]=__builtin_fmaf(x1,wb.x,acc[1][4]);
      acc[1][5]=__builtin_fmaf(x1,wb.y,acc[1][5]);
      acc[1][6]=__builtin_fmaf(x1,wb.z,acc[1][6]);
      acc[1][7]=__builtin_fmaf(x1,wb.w,acc[1][7]);
    }
  }
#pragma unroll
  for (int j=0;j<8;j++){
    int o=h0+j;
    float2 we=*(const float2*)(Wout + (size_t)o*GEO_MID_ + 128);
#pragma unroll
    for (int a=0;a<2;a++){
      float v=acc[a][j];
      v=__builtin_fmaf(-1.f, we.x, v);
      v=__builtin_fmaf(ssv[2*gsub+a], we.y, v);
      xout[(size_t)(g0+2*gsub+a)*256 + o]=v;
    }
  }
}

// ---------------------------------------------------------------- FEAT fused
// (unchanged from round 7)
__global__ __launch_bounds__(256) void feat_kernel(
    const float* __restrict__ feats, const u16t* __restrict__ gidx16,
    const float* __restrict__ W1, const float* __restrict__ b1,
    const float* __restrict__ Wout, const float* __restrict__ bout,
    float* __restrict__ xout)
{
  __shared__ float smem[12800];                      // 51.2 KB
  float (*Xs)[68]  = (float(*)[68])smem;
  float (*Ws)[128] = (float(*)[128])(smem + 64*68);
  float (*Hs)[68]  = (float(*)[68])smem;
  float (*WoS)[128]= (float(*)[128])(smem + 128*68);
  const int t=threadIdx.x;
  const int g0=blockIdx.x*64;
  const int gsub=t>>4;
  const int h0=(t&15)*8;
  const int glx=t>>2, fq=(t&3)*16;
  const int hw=t>>1, fw0=(t&1)*32;
  const int fw1=(t&1)*16;
  const int gld=g0+glx, bld=gld>>10;
  float acc[4][8];
#pragma unroll
  for (int a=0;a<4;a++)
#pragma unroll
    for (int j=0;j<8;j++) acc[a][j]=0.f;

  for (int kk=0;kk<K_;kk++){
    int nidx=gidx16[gld*K_+kk];
    const float* fr=feats + ((size_t)bld*N_+(size_t)nidx)*FEAT_ + fq;
    float4 p[4];
#pragma unroll
    for (int e=0;e<4;e++) p[e]=((const float4*)fr)[e];
    const float* wr=W1 + (size_t)hw*FEAT_IN_ + kk*64 + fw0;
    float4 wv[8];
#pragma unroll
    for (int e=0;e<8;e++) wv[e]=((const float4*)wr)[e];
#pragma unroll
    for (int e=0;e<4;e++){
      Xs[fq+4*e+0][glx]=p[e].x;
      Xs[fq+4*e+1][glx]=p[e].y;
      Xs[fq+4*e+2][glx]=p[e].z;
      Xs[fq+4*e+3][glx]=p[e].w;
    }
#pragma unroll
    for (int e=0;e<8;e++){
      Ws[fw0+4*e+0][hw]=wv[e].x;
      Ws[fw0+4*e+1][hw]=wv[e].y;
      Ws[fw0+4*e+2][hw]=wv[e].z;
      Ws[fw0+4*e+3][hw]=wv[e].w;
    }
    __syncthreads();
#pragma unroll 4
    for (int k2=0;k2<64;k2++){
      float4 xv=*(const float4*)&Xs[k2][4*gsub];
      const float* wp=&Ws[k2][h0];
      float4 wa=*(const float4*)wp;
      float4 wb=*(const float4*)(wp+4);
      float xr[4]={xv.x,xv.y,xv.z,xv.w};
      float wf[8]={wa.x,wa.y,wa.z,wa.w,wb.x,wb.y,wb.z,wb.w};
#pragma unroll
      for (int a=0;a<4;a++)
#pragma unroll
        for (int j=0;j<8;j++)
          acc[a][j]=__builtin_fmaf(xr[a],wf[j],acc[a][j]);
    }
    __syncthreads();
  }
#pragma unroll
  for (int j=0;j<8;j++){
    float bv=b1[h0+j];
#pragma unroll
    for (int a=0;a<4;a++)
      Hs[h0+j][4*gsub+a]=fmaxf(__fadd_rn(acc[a][j],bv),0.f);
  }
  float ac2[4][8];
#pragma unroll
  for (int a=0;a<4;a++)
#pragma unroll
    for (int j=0;j<8;j++) ac2[a][j]=0.f;
  for (int c=0;c<4;c++){
    const float* wr2=Wout + (size_t)hw*H_ + c*32 + fw1;
    float4 w2[4];
#pragma unroll
    for (int e=0;e<4;e++) w2[e]=((const float4*)wr2)[e];
    __syncthreads();
#pragma unroll
    for (int e=0;e<4;e++){
      WoS[fw1+4*e+0][hw]=w2[e].x;
      WoS[fw1+4*e+1][hw]=w2[e].y;
      WoS[fw1+4*e+2][hw]=w2[e].z;
      WoS[fw1+4*e+3][hw]=w2[e].w;
    }
    __syncthreads();
#pragma unroll 4
    for (int k2=0;k2<32;k2++){
      float4 xv=*(const float4*)&Hs[c*32+k2][4*gsub];
      const float* wp=&WoS[k2][h0];
      float4 wa=*(const float4*)wp;
      float4 wb=*(const float4*)(wp+4);
      float xr[4]={xv.x,xv.y,xv.z,xv.w};
      float wf[8]={wa.x,wa.y,wa.z,wa.w,wb.x,wb.y,wb.z,wb.w};
#pragma unroll
      for (int a=0;a<4;a++)
#pragma unroll
        for (int j=0;j<8;j++)
          ac2[a][j]=__builtin_fmaf(xr[a],wf[j],ac2[a][j]);
    }
  }
#pragma unroll
  for (int j=0;j<8;j++){
    float bv=bout[h0+j];
#pragma unroll
    for (int a=0;a<4;a++)
      xout[(size_t)(g0+4*gsub+a)*256+128+h0+j]=__fadd_rn(ac2[a][j],bv);
  }
}

// ----------------------------------------------------------------
extern "C" void kernel_launch(void* const* d_in, const int* in_sizes, int n_in,
                              void* d_out, int out_size, void* d_ws, size_t ws_size,
                              hipStream_t stream) {
  const float* xyz  =(const float*)d_in[0];
  const float* feats=(const float*)d_in[1];
  const float* gW1  =(const float*)d_in[2];
  const float* gWout=(const float*)d_in[3];
  const float* fW1  =(const float*)d_in[4];
  const float* fb1  =(const float*)d_in[5];
  const float* fWout=(const float*)d_in[6];
  const float* fbout=(const float*)d_in[7];
  float* out=(float*)d_out;

  u16t* gidx16=(u16t*)d_ws;          // 1 MB
  float* xout = out + (size_t)B_*M_*3;

  fps_kernel <<<dim3(B_),          dim3(256), 0, stream>>>(xyz, out);
  knn_kernel <<<dim3((B_*M_)/4),   dim3(256), 0, stream>>>(xyz, out, gidx16);
  geo_kernel <<<dim3((B_*M_)/32),  dim3(256), 0, stream>>>(xyz, out, gidx16, gW1, gWout, xout);
  feat_kernel<<<dim3((B_*M_)/64),  dim3(256), 0, stream>>>(feats, gidx16, fW1, fb1, fWout, fbout, xout);
}

// Round 9
// 2002.204 us; speedup vs baseline: 1.0931x; 1.0931x over previous
//
#include <hip/hip_runtime.h>
#include <float.h>

#define B_ 16
#define N_ 4096
#define M_ 1024
#define K_ 32
#define FEAT_ 64
#define H_ 128
#define GEO_IN_ 160
#define GEO_MID_ 130
#define FEAT_IN_ 2048

typedef unsigned short u16t;
typedef float v2f __attribute__((ext_vector_type(2)));

// ---- wave64 reductions in the VALU pipe (DPP), identity-preserving ----
#define DPP_STEP_MAX(ctrl) \
  t=(unsigned)__builtin_amdgcn_update_dpp((int)v,(int)v,(ctrl),0xf,0xf,false); \
  v=(t>v)?t:v;
#define DPP_STEP_MIN(ctrl) \
  t=(unsigned)__builtin_amdgcn_update_dpp((int)v,(int)v,(ctrl),0xf,0xf,false); \
  v=(t<v)?t:v;

__device__ __forceinline__ unsigned wave_max_u32(unsigned v){
  unsigned t;
  DPP_STEP_MAX(0x111) DPP_STEP_MAX(0x112) DPP_STEP_MAX(0x114) DPP_STEP_MAX(0x118)
  DPP_STEP_MAX(0x142) DPP_STEP_MAX(0x143)
  return (unsigned)__builtin_amdgcn_readlane((int)v,63);
}
__device__ __forceinline__ unsigned wave_min_u32(unsigned v){
  unsigned t;
  DPP_STEP_MIN(0x111) DPP_STEP_MIN(0x112) DPP_STEP_MIN(0x114) DPP_STEP_MIN(0x118)
  DPP_STEP_MIN(0x142) DPP_STEP_MIN(0x143)
  return (unsigned)__builtin_amdgcn_readlane((int)v,63);
}

// ---------------------------------------------------------------- FPS
// ONE WAVE per batch (64 thr), 64 pts/lane as 32 float2 pairs -> packed-fp32
// VALU (v_pk_*). NO barriers, NO cross-wave traffic. Per step: packed dist
// update + running value pk-max -> DPP u32 max -> index recovery (descending
// first-match scan, exact) -> DPP u32 min -> winner coords via broadcast
// ds_read from LDS mirror. contract(off) => mul/add unfused, bit-exact.
// Semantics: max dist, tie -> smallest index.
__global__ __launch_bounds__(64) void fps_kernel(
    const float* __restrict__ xyz, float* __restrict__ outc)
{
#pragma clang fp contract(off)
  const int b = blockIdx.x, lane = threadIdx.x;
  const float* xb = xyz + (size_t)b*(N_*3);
  __shared__ float spt[N_*3];            // 48 KB mirror for winner-coord reads
  for (int v=lane; v<(N_*3)/4; v+=64)
    ((float4*)spt)[v]=((const float4*)xb)[v];
  v2f px[32],py[32],pz[32],dd[32];
#pragma unroll
  for (int j=0;j<32;j++){
    int i0=(lane+64*(2*j))*3, i1=(lane+64*(2*j+1))*3;
    px[j]=(v2f){xb[i0],  xb[i1]};
    py[j]=(v2f){xb[i0+1],xb[i1+1]};
    pz[j]=(v2f){xb[i0+2],xb[i1+2]};
    dd[j]=(v2f){FLT_MAX,FLT_MAX};
  }
  float lx=xb[0], ly=xb[1], lz=xb[2];
  if (lane==0){
    size_t cb=(size_t)b*M_*3;
    outc[cb]=lx; outc[cb+1]=ly; outc[cb+2]=lz;
  }
  for (int t=1;t<M_;t++){
    v2f lxx={lx,lx}, lyy={ly,ly}, lzz={lz,lz};
    v2f bdv={-FLT_MAX,-FLT_MAX};
#pragma unroll
    for (int j=0;j<32;j++){
      v2f dx=px[j]-lxx, dy=py[j]-lyy, dz=pz[j]-lzz;
      v2f s=(dx*dx+dy*dy)+dz*dz;                 // contract off: mul,mul,add,mul,add (per half)
      v2f nd=__builtin_elementwise_min(dd[j],s); // exact fminf per half
      dd[j]=nd;
      bdv=__builtin_elementwise_max(bdv,nd);     // value-only running max (order-free)
    }
    float bd=fmaxf(bdv.x,bdv.y);
    unsigned smaxu=wave_max_u32(__float_as_uint(bd));   // dd>=0 => bits monotone
    float smax=__uint_as_float(smaxu);
    // index recovery: descending scan, later (smaller-idx) writes win; x (even
    // idx) checked after y => exact first-max index per lane
    unsigned ic=0x7FFFFFFFu;
#pragma unroll
    for (int j=31;j>=0;j--){
      if (dd[j].y==smax) ic=(unsigned)(lane+64*(2*j+1));
      if (dd[j].x==smax) ic=(unsigned)(lane+64*(2*j));
    }
    unsigned ci=wave_min_u32(ic);                // global smallest attaining idx
    lx=spt[3*ci]; ly=spt[3*ci+1]; lz=spt[3*ci+2];   // broadcast ds_read
    if (lane==0){
      size_t cb=((size_t)b*M_+(size_t)t)*3;
      outc[cb]=lx; outc[cb+1]=ly; outc[cb+2]=lz;
    }
  }
}

// ---------------------------------------------------------------- KNN
// (unchanged from round 8 — bit-identical selection, top-2 cache)
__global__ __launch_bounds__(256) void knn_kernel(
    const float* __restrict__ xyz, const float* __restrict__ outc,
    u16t* __restrict__ gidx16)
{
  const int w = blockIdx.x*4 + (threadIdx.x>>6);
  const int lane = threadIdx.x & 63;
  const int b = w >> 10;
  const float* xb = xyz + (size_t)b*(N_*3);
  float cx=outc[(size_t)w*3], cy=outc[(size_t)w*3+1], cz=outc[(size_t)w*3+2];
  float c2=__fadd_rn(__fadd_rn(__fmul_rn(cx,cx),__fmul_rn(cy,cy)),__fmul_rn(cz,cz));
  float dl[64];
#pragma unroll
  for (int j=0;j<64;j++){
    int i = lane + 64*j;
    float xx=xb[i*3], xy=xb[i*3+1], xz=xb[i*3+2];
    float x2=__fadd_rn(__fadd_rn(__fmul_rn(xx,xx),__fmul_rn(xy,xy)),__fmul_rn(xz,xz));
    float dt=__fadd_rn(__fadd_rn(__fmul_rn(cx,xx),__fmul_rn(cy,xy)),__fmul_rn(cz,xz));
    dl[j]=__fsub_rn(__fadd_rn(c2,x2),__fmul_rn(2.f,dt));
  }
  float m1=FLT_MAX,m2=FLT_MAX; int j1=64,j2=64;
#pragma unroll
  for (int j=0;j<64;j++){
    float d=dl[j];
    bool b1=(d<m1), b2=(d<m2);
    float nm2=b1?m1:(b2?d:m2); int nj2=b1?j1:(b2?j:j2);
    float nm1=b1?d:m1;         int nj1=b1?j:j1;
    m1=nm1;j1=nj1;m2=nm2;j2=nj2;
  }
  unsigned long long popped=0ull;
  const int wb = w*K_;
  for (int k=0;k<K_;k++){
    unsigned u=__float_as_uint(m1);
    u = (u&0x80000000u) ? ~u : (u|0x80000000u);
    unsigned smin=wave_min_u32(u);
    unsigned cand=(u==smin)?(unsigned)(lane+64*j1):0xFFFFFFFFu;
    unsigned widx=wave_min_u32(cand);
    if (lane==0) gidx16[wb+k]=(u16t)widx;
    if ((widx & 63)==(unsigned)lane){
      popped |= (1ull<<j1);
      if (j2<64){ m1=m2; j1=j2; m2=FLT_MAX; j2=64; }
      else {
        m1=FLT_MAX; m2=FLT_MAX; j1=64; j2=64;
#pragma unroll
        for (int j=0;j<64;j++){
          float d=((popped>>j)&1ull)?FLT_MAX:dl[j];
          bool b1=(d<m1), b2=(d<m2);
          float nm2=b1?m1:(b2?d:m2); int nj2=b1?j1:(b2?j:j2);
          float nm1=b1?d:m1;         int nj1=b1?j:j1;
          m1=nm1;j1=nj1;m2=nm2;j2=nj2;
        }
      }
    }
  }
}

// ---------------------------------------------------------------- GEO fused (GEMM-style)
// (unchanged from round 8)
__global__ __launch_bounds__(256) void geo_kernel(
    const float* __restrict__ xyz, const float* __restrict__ outc,
    const u16t* __restrict__ gidx16, const float* __restrict__ W1,
    const float* __restrict__ Wout, float* __restrict__ xout)
{
  __shared__ float smem[160*33 + 64*128 + 32];
  float (*Es)[33]  = (float(*)[33])smem;
  float (*Hs)[33]  = (float(*)[33])smem;
  float (*Ws)[128] = (float(*)[128])(smem + 160*33);
  float* ssv = smem + 160*33 + 64*128;

  const int t=threadIdx.x;
  const int g0=blockIdx.x*32;
  for (int p=t; p<1024; p+=256){
    int g=p>>5, kk=p&31;
    int gg=g0+g, b=gg>>10;
    int idx=gidx16[gg*K_+kk];
    const float* pt = xyz + ((size_t)b*N_+(size_t)idx)*3;
    const float* cc = outc + (size_t)gg*3;
    float dx=__fsub_rn(pt[0],cc[0]);
    float dy=__fsub_rn(pt[1],cc[1]);
    float dz=__fsub_rn(pt[2],cc[2]);
    float sq=__fadd_rn(__fadd_rn(__fmul_rn(dx,dx),__fmul_rn(dy,dy)),__fmul_rn(dz,dz));
    int r=5*kk;
    Es[r][g]=dx; Es[r+1][g]=dy; Es[r+2][g]=dz;
    Es[r+3][g]=-1.f; Es[r+4][g]=__fmul_rn(-0.5f,sq);
  }
  const int gsub=t>>4, hsub=t&15, h0=hsub*8;
  const int hw=t>>1;
  float acc[2][8];
#pragma unroll
  for (int a=0;a<2;a++)
#pragma unroll
    for (int j=0;j<8;j++) acc[a][j]=0.f;
  __syncthreads();

  for (int c=0;c<3;c++){
    int i0=c*64;
    if (c<2){
      int fw0=(t&1)*32;
      const float* wr = W1 + (size_t)hw*GEO_IN_ + i0 + fw0;
      float4 wv[8];
#pragma unroll
      for (int e=0;e<8;e++) wv[e]=((const float4*)wr)[e];
#pragma unroll
      for (int e=0;e<8;e++){
        Ws[fw0+4*e+0][hw]=wv[e].x;
        Ws[fw0+4*e+1][hw]=wv[e].y;
        Ws[fw0+4*e+2][hw]=wv[e].z;
        Ws[fw0+4*e+3][hw]=wv[e].w;
      }
    } else {
      int fw0=(t&1)*16;
      const float* wr = W1 + (size_t)hw*GEO_IN_ + 128 + fw0;
      float4 wv[4];
#pragma unroll
      for (int e=0;e<4;e++) wv[e]=((const float4*)wr)[e];
#pragma unroll
      for (int e=0;e<4;e++){
        Ws[fw0+4*e+0][hw]=wv[e].x;
        Ws[fw0+4*e+1][hw]=wv[e].y;
        Ws[fw0+4*e+2][hw]=wv[e].z;
        Ws[fw0+4*e+3][hw]=wv[e].w;
      }
    }
    __syncthreads();
    int len=(c==2)?32:64;
    for (int k2=0;k2<len;k2++){
      float x0=Es[i0+k2][2*gsub], x1=Es[i0+k2][2*gsub+1];
      const float* wp=&Ws[k2][h0];
      float4 wa=*(const float4*)wp;
      float4 wb=*(const float4*)(wp+4);
      acc[0][0]=__builtin_fmaf(x0,wa.x,acc[0][0]);
      acc[0][1]=__builtin_fmaf(x0,wa.y,acc[0][1]);
      acc[0][2]=__builtin_fmaf(x0,wa.z,acc[0][2]);
      acc[0][3]=__builtin_fmaf(x0,wa.w,acc[0][3]);
      acc[0][4]=__builtin_fmaf(x0,wb.x,acc[0][4]);
      acc[0][5]=__builtin_fmaf(x0,wb.y,acc[0][5]);
      acc[0][6]=__builtin_fmaf(x0,wb.z,acc[0][6]);
      acc[0][7]=__builtin_fmaf(x0,wb.w,acc[0][7]);
      acc[1][0]=__builtin_fmaf(x1,wa.x,acc[1][0]);
      acc[1][1]=__builtin_fmaf(x1,wa.y,acc[1][1]);
      acc[1][2]=__builtin_fmaf(x1,wa.z,acc[1][2]);
      acc[1][3]=__builtin_fmaf(x1,wa.w,acc[1][3]);
      acc[1][4]=__builtin_fmaf(x1,wb.x,acc[1][4]);
      acc[1][5]=__builtin_fmaf(x1,wb.y,acc[1][5]);
      acc[1][6]=__builtin_fmaf(x1,wb.z,acc[1][6]);
      acc[1][7]=__builtin_fmaf(x1,wb.w,acc[1][7]);
    }
    __syncthreads();
  }
#pragma unroll
  for (int a=0;a<2;a++)
#pragma unroll
    for (int j=0;j<8;j++)
      Hs[h0+j][2*gsub+a]=acc[a][j];
  __syncthreads();
  if (t<32){
    float ss=0.f;
    for (int h=0;h<H_;h++){ float v=Hs[h][t]; ss=__builtin_fmaf(v,v,ss); }
    ssv[t]=__fmul_rn(-0.5f,ss);
  }
#pragma unroll
  for (int a=0;a<2;a++)
#pragma unroll
    for (int j=0;j<8;j++) acc[a][j]=0.f;
  for (int c=0;c<2;c++){
    int i0=c*64;
    int fw0=(t&1)*32;
    const float* wr = Wout + (size_t)hw*GEO_MID_ + i0 + fw0;
    float2 wv2[16];
#pragma unroll
    for (int e=0;e<16;e++) wv2[e]=((const float2*)wr)[e];
    __syncthreads();
#pragma unroll
    for (int e=0;e<16;e++){
      Ws[fw0+2*e+0][hw]=wv2[e].x;
      Ws[fw0+2*e+1][hw]=wv2[e].y;
    }
    __syncthreads();
    for (int k2=0;k2<64;k2++){
      float x0=Hs[i0+k2][2*gsub], x1=Hs[i0+k2][2*gsub+1];
      const float* wp=&Ws[k2][h0];
      float4 wa=*(const float4*)wp;
      float4 wb=*(const float4*)(wp+4);
      acc[0][0]=__builtin_fmaf(x0,wa.x,acc[0][0]);
      acc[0][1]=__builtin_fmaf(x0,wa.y,acc[0][1]);
      acc[0][2]=__builtin_fmaf(x0,wa.z,acc[0][2]);
      acc[0][3]=__builtin_fmaf(x0,wa.w,acc[0][3]);
      acc[0][4]=__builtin_fmaf(x0,wb.x,acc[0][4]);
      acc[0][5]=__builtin_fmaf(x0,wb.y,acc[0][5]);
      acc[0][6]=__builtin_fmaf(x0,wb.z,acc[0][6]);
      acc[0][7]=__builtin_fmaf(x0,wb.w,acc[0][7]);
      acc[1][0]=__builtin_fmaf(x1,wa.x,acc[1][0]);
      acc[1][1]=__builtin_fmaf(x1,wa.y,acc[1][1]);
      acc[1][2]=__builtin_fmaf(x1,wa.z,acc[1][2]);
      acc[1][3]=__builtin_fmaf(x1,wa.w,acc[1][3]);
      acc[1][4]=__builtin_fmaf(x1,wb.x,acc[1][4]);
      acc[1][5]=__builtin_fmaf(x1,wb.y,acc[1][5]);
      acc[1][6]=__builtin_fmaf(x1,wb.z,acc[1][6]);
      acc[1][7]=__builtin_fmaf(x1,wb.w,acc[1][7]);
    }
  }
#pragma unroll
  for (int j=0;j<8;j++){
    int o=h0+j;
    float2 we=*(const float2*)(Wout + (size_t)o*GEO_MID_ + 128);
#pragma unroll
    for (int a=0;a<2;a++){
      float v=acc[a][j];
      v=__builtin_fmaf(-1.f, we.x, v);
      v=__builtin_fmaf(ssv[2*gsub+a], we.y, v);
      xout[(size_t)(g0+2*gsub+a)*256 + o]=v;
    }
  }
}

// ---------------------------------------------------------------- FEAT fused
// Round-8 structure + register double-buffer: kk+1 global loads issued AFTER
// the post-write barrier so they overlap the inner loop (not drained by the
// next barrier until a full inner loop later). Accumulation order unchanged.
__global__ __launch_bounds__(256) void feat_kernel(
    const float* __restrict__ feats, const u16t* __restrict__ gidx16,
    const float* __restrict__ W1, const float* __restrict__ b1,
    const float* __restrict__ Wout, const float* __restrict__ bout,
    float* __restrict__ xout)
{
  __shared__ float smem[12800];                      // 51.2 KB
  float (*Xs)[68]  = (float(*)[68])smem;
  float (*Ws)[128] = (float(*)[128])(smem + 64*68);
  float (*Hs)[68]  = (float(*)[68])smem;
  float (*WoS)[128]= (float(*)[128])(smem + 128*68);
  const int t=threadIdx.x;
  const int g0=blockIdx.x*64;
  const int gsub=t>>4;
  const int h0=(t&15)*8;
  const int glx=t>>2, fq=(t&3)*16;
  const int hw=t>>1, fw0=(t&1)*32;
  const int fw1=(t&1)*16;
  const int gld=g0+glx, bld=gld>>10;
  float acc[4][8];
#pragma unroll
  for (int a=0;a<4;a++)
#pragma unroll
    for (int j=0;j<8;j++) acc[a][j]=0.f;

  // preload kk=0 data and kk=1 index
  float4 p[4], wv[8];
  {
    int nidx0 = gidx16[gld*K_+0];
    const float* fr=feats + ((size_t)bld*N_+(size_t)nidx0)*FEAT_ + fq;
#pragma unroll
    for (int e=0;e<4;e++) p[e]=((const float4*)fr)[e];
    const float* wr=W1 + (size_t)hw*FEAT_IN_ + fw0;
#pragma unroll
    for (int e=0;e<8;e++) wv[e]=((const float4*)wr)[e];
  }
  int nidx_n = gidx16[gld*K_+1];

  for (int kk=0;kk<K_;kk++){
    __syncthreads();                     // prev inner-loop readers done
#pragma unroll
    for (int e=0;e<4;e++){
      Xs[fq+4*e+0][glx]=p[e].x;
      Xs[fq+4*e+1][glx]=p[e].y;
      Xs[fq+4*e+2][glx]=p[e].z;
      Xs[fq+4*e+3][glx]=p[e].w;
    }
#pragma unroll
    for (int e=0;e<8;e++){
      Ws[fw0+4*e+0][hw]=wv[e].x;
      Ws[fw0+4*e+1][hw]=wv[e].y;
      Ws[fw0+4*e+2][hw]=wv[e].z;
      Ws[fw0+4*e+3][hw]=wv[e].w;
    }
    __syncthreads();                     // writes visible
    // prefetch kk+1 data (+ kk+2 index) — overlaps inner loop below
    float4 pn[4], wn[8];
    int nidx_n2=0;
    if (kk+1<K_){
      const float* frn=feats + ((size_t)bld*N_+(size_t)nidx_n)*FEAT_ + fq;
#pragma unroll
      for (int e=0;e<4;e++) pn[e]=((const float4*)frn)[e];
      const float* wrn=W1 + (size_t)hw*FEAT_IN_ + (kk+1)*64 + fw0;
#pragma unroll
      for (int e=0;e<8;e++) wn[e]=((const float4*)wrn)[e];
      if (kk+2<K_) nidx_n2 = gidx16[gld*K_+kk+2];
    }
#pragma unroll 4
    for (int k2=0;k2<64;k2++){
      float4 xv=*(const float4*)&Xs[k2][4*gsub];
      const float* wp=&Ws[k2][h0];
      float4 wa=*(const float4*)wp;
      float4 wb=*(const float4*)(wp+4);
      float xr[4]={xv.x,xv.y,xv.z,xv.w};
      float wf[8]={wa.x,wa.y,wa.z,wa.w,wb.x,wb.y,wb.z,wb.w};
#pragma unroll
      for (int a=0;a<4;a++)
#pragma unroll
        for (int j=0;j<8;j++)
          acc[a][j]=__builtin_fmaf(xr[a],wf[j],acc[a][j]);
    }
    if (kk+1<K_){
#pragma unroll
      for (int e=0;e<4;e++) p[e]=pn[e];
#pragma unroll
      for (int e=0;e<8;e++) wv[e]=wn[e];
      nidx_n=nidx_n2;
    }
  }
  __syncthreads();                       // inner-loop readers done before alias
#pragma unroll
  for (int j=0;j<8;j++){
    float bv=b1[h0+j];
#pragma unroll
    for (int a=0;a<4;a++)
      Hs[h0+j][4*gsub+a]=fmaxf(__fadd_rn(acc[a][j],bv),0.f);
  }
  float ac2[4][8];
#pragma unroll
  for (int a=0;a<4;a++)
#pragma unroll
    for (int j=0;j<8;j++) ac2[a][j]=0.f;
  for (int c=0;c<4;c++){
    const float* wr2=Wout + (size_t)hw*H_ + c*32 + fw1;
    float4 w2[4];
#pragma unroll
    for (int e=0;e<4;e++) w2[e]=((const float4*)wr2)[e];
    __syncthreads();
#pragma unroll
    for (int e=0;e<4;e++){
      WoS[fw1+4*e+0][hw]=w2[e].x;
      WoS[fw1+4*e+1][hw]=w2[e].y;
      WoS[fw1+4*e+2][hw]=w2[e].z;
      WoS[fw1+4*e+3][hw]=w2[e].w;
    }
    __syncthreads();
#pragma unroll 4
    for (int k2=0;k2<32;k2++){
      float4 xv=*(const float4*)&Hs[c*32+k2][4*gsub];
      const float* wp=&WoS[k2][h0];
      float4 wa=*(const float4*)wp;
      float4 wb=*(const float4*)(wp+4);
      float xr[4]={xv.x,xv.y,xv.z,xv.w};
      float wf[8]={wa.x,wa.y,wa.z,wa.w,wb.x,wb.y,wb.z,wb.w};
#pragma unroll
      for (int a=0;a<4;a++)
#pragma unroll
        for (int j=0;j<8;j++)
          ac2[a][j]=__builtin_fmaf(xr[a],wf[j],ac2[a][j]);
    }
  }
#pragma unroll
  for (int j=0;j<8;j++){
    float bv=bout[h0+j];
#pragma unroll
    for (int a=0;a<4;a++)
      xout[(size_t)(g0+4*gsub+a)*256+128+h0+j]=__fadd_rn(ac2[a][j],bv);
  }
}

// ----------------------------------------------------------------
extern "C" void kernel_launch(void* const* d_in, const int* in_sizes, int n_in,
                              void* d_out, int out_size, void* d_ws, size_t ws_size,
                              hipStream_t stream) {
  const float* xyz  =(const float*)d_in[0];
  const float* feats=(const float*)d_in[1];
  const float* gW1  =(const float*)d_in[2];
  const float* gWout=(const float*)d_in[3];
  const float* fW1  =(const float*)d_in[4];
  const float* fb1  =(const float*)d_in[5];
  const float* fWout=(const float*)d_in[6];
  const float* fbout=(const float*)d_in[7];
  float* out=(float*)d_out;

  u16t* gidx16=(u16t*)d_ws;          // 1 MB
  float* xout = out + (size_t)B_*M_*3;

  fps_kernel <<<dim3(B_),          dim3(64),  0, stream>>>(xyz, out);
  knn_kernel <<<dim3((B_*M_)/4),   dim3(256), 0, stream>>>(xyz, out, gidx16);
  geo_kernel <<<dim3((B_*M_)/32),  dim3(256), 0, stream>>>(xyz, out, gidx16, gW1, gWout, xout);
  feat_kernel<<<dim3((B_*M_)/64),  dim3(256), 0, stream>>>(feats, gidx16, fW1, fb1, fWout, fbout, xout);
}

// Round 10
// 2000.472 us; speedup vs baseline: 1.0941x; 1.0009x over previous
//
#include <hip/hip_runtime.h>
#include <float.h>

#define B_ 16
#define N_ 4096
#define M_ 1024
#define K_ 32
#define FEAT_ 64
#define H_ 128
#define GEO_IN_ 160
#define GEO_MID_ 130
#define FEAT_IN_ 2048

typedef unsigned short u16t;
typedef float v2f __attribute__((ext_vector_type(2)));

// ---- wave64 reductions in the VALU pipe (DPP), identity-preserving ----
#define DPP_STEP_MAX(ctrl) \
  t=(unsigned)__builtin_amdgcn_update_dpp((int)v,(int)v,(ctrl),0xf,0xf,false); \
  v=(t>v)?t:v;
#define DPP_STEP_MIN(ctrl) \
  t=(unsigned)__builtin_amdgcn_update_dpp((int)v,(int)v,(ctrl),0xf,0xf,false); \
  v=(t<v)?t:v;

__device__ __forceinline__ unsigned wave_max_u32(unsigned v){
  unsigned t;
  DPP_STEP_MAX(0x111) DPP_STEP_MAX(0x112) DPP_STEP_MAX(0x114) DPP_STEP_MAX(0x118)
  DPP_STEP_MAX(0x142) DPP_STEP_MAX(0x143)
  return (unsigned)__builtin_amdgcn_readlane((int)v,63);
}
__device__ __forceinline__ unsigned wave_min_u32(unsigned v){
  unsigned t;
  DPP_STEP_MIN(0x111) DPP_STEP_MIN(0x112) DPP_STEP_MIN(0x114) DPP_STEP_MIN(0x118)
  DPP_STEP_MIN(0x142) DPP_STEP_MIN(0x143)
  return (unsigned)__builtin_amdgcn_readlane((int)v,63);
}

// ---------------------------------------------------------------- FPS
// ONE WAVE per batch, 64 pts/lane as 32 float2 pairs -> packed-fp32 VALU.
// __launch_bounds__(64,1): allow up to 512 VGPRs so px/py/pz/dd (256 VGPRs)
// stay register-resident — r9's identical code spilled at the default cap
// (VGPR_Count=136, +43MB scratch FETCH). Algorithm proven bit-identical (r9
// passed, absmax canary unchanged). No barriers, no cross-wave traffic.
// Semantics: max dist, tie -> smallest index; contract(off) => unfused.
__global__ __launch_bounds__(64,1) void fps_kernel(
    const float* __restrict__ xyz, float* __restrict__ outc)
{
#pragma clang fp contract(off)
  const int b = blockIdx.x, lane = threadIdx.x;
  const float* xb = xyz + (size_t)b*(N_*3);
  __shared__ float spt[N_*3];            // 48 KB mirror for winner-coord reads
  for (int v=lane; v<(N_*3)/4; v+=64)
    ((float4*)spt)[v]=((const float4*)xb)[v];
  v2f px[32],py[32],pz[32],dd[32];
#pragma unroll
  for (int j=0;j<32;j++){
    int i0=(lane+64*(2*j))*3, i1=(lane+64*(2*j+1))*3;
    px[j]=(v2f){xb[i0],  xb[i1]};
    py[j]=(v2f){xb[i0+1],xb[i1+1]};
    pz[j]=(v2f){xb[i0+2],xb[i1+2]};
    dd[j]=(v2f){FLT_MAX,FLT_MAX};
  }
  float lx=xb[0], ly=xb[1], lz=xb[2];
  if (lane==0){
    size_t cb=(size_t)b*M_*3;
    outc[cb]=lx; outc[cb+1]=ly; outc[cb+2]=lz;
  }
  for (int t=1;t<M_;t++){
    v2f lxx={lx,lx}, lyy={ly,ly}, lzz={lz,lz};
    v2f bdv={-FLT_MAX,-FLT_MAX};
#pragma unroll
    for (int j=0;j<32;j++){
      v2f dx=px[j]-lxx, dy=py[j]-lyy, dz=pz[j]-lzz;
      v2f s=(dx*dx+dy*dy)+dz*dz;                 // contract off
      v2f nd=__builtin_elementwise_min(dd[j],s);
      dd[j]=nd;
      bdv=__builtin_elementwise_max(bdv,nd);     // value-only running max
    }
    float bd=fmaxf(bdv.x,bdv.y);
    unsigned smaxu=wave_max_u32(__float_as_uint(bd));   // dd>=0 => bits monotone
    float smax=__uint_as_float(smaxu);
    // index recovery: descending scan, later (smaller-idx) writes win
    unsigned ic=0x7FFFFFFFu;
#pragma unroll
    for (int j=31;j>=0;j--){
      if (dd[j].y==smax) ic=(unsigned)(lane+64*(2*j+1));
      if (dd[j].x==smax) ic=(unsigned)(lane+64*(2*j));
    }
    unsigned ci=wave_min_u32(ic);                // global smallest attaining idx
    lx=spt[3*ci]; ly=spt[3*ci+1]; lz=spt[3*ci+2];   // broadcast ds_read
    if (lane==0){
      size_t cb=((size_t)b*M_+(size_t)t)*3;
      outc[cb]=lx; outc[cb+1]=ly; outc[cb+2]=lz;
    }
  }
}

// ---------------------------------------------------------------- KNN
// (unchanged from round 9 — bit-identical selection, top-2 cache)
__global__ __launch_bounds__(256) void knn_kernel(
    const float* __restrict__ xyz, const float* __restrict__ outc,
    u16t* __restrict__ gidx16)
{
  const int w = blockIdx.x*4 + (threadIdx.x>>6);
  const int lane = threadIdx.x & 63;
  const int b = w >> 10;
  const float* xb = xyz + (size_t)b*(N_*3);
  float cx=outc[(size_t)w*3], cy=outc[(size_t)w*3+1], cz=outc[(size_t)w*3+2];
  float c2=__fadd_rn(__fadd_rn(__fmul_rn(cx,cx),__fmul_rn(cy,cy)),__fmul_rn(cz,cz));
  float dl[64];
#pragma unroll
  for (int j=0;j<64;j++){
    int i = lane + 64*j;
    float xx=xb[i*3], xy=xb[i*3+1], xz=xb[i*3+2];
    float x2=__fadd_rn(__fadd_rn(__fmul_rn(xx,xx),__fmul_rn(xy,xy)),__fmul_rn(xz,xz));
    float dt=__fadd_rn(__fadd_rn(__fmul_rn(cx,xx),__fmul_rn(cy,xy)),__fmul_rn(cz,xz));
    dl[j]=__fsub_rn(__fadd_rn(c2,x2),__fmul_rn(2.f,dt));
  }
  float m1=FLT_MAX,m2=FLT_MAX; int j1=64,j2=64;
#pragma unroll
  for (int j=0;j<64;j++){
    float d=dl[j];
    bool b1=(d<m1), b2=(d<m2);
    float nm2=b1?m1:(b2?d:m2); int nj2=b1?j1:(b2?j:j2);
    float nm1=b1?d:m1;         int nj1=b1?j:j1;
    m1=nm1;j1=nj1;m2=nm2;j2=nj2;
  }
  unsigned long long popped=0ull;
  const int wb = w*K_;
  for (int k=0;k<K_;k++){
    unsigned u=__float_as_uint(m1);
    u = (u&0x80000000u) ? ~u : (u|0x80000000u);
    unsigned smin=wave_min_u32(u);
    unsigned cand=(u==smin)?(unsigned)(lane+64*j1):0xFFFFFFFFu;
    unsigned widx=wave_min_u32(cand);
    if (lane==0) gidx16[wb+k]=(u16t)widx;
    if ((widx & 63)==(unsigned)lane){
      popped |= (1ull<<j1);
      if (j2<64){ m1=m2; j1=j2; m2=FLT_MAX; j2=64; }
      else {
        m1=FLT_MAX; m2=FLT_MAX; j1=64; j2=64;
#pragma unroll
        for (int j=0;j<64;j++){
          float d=((popped>>j)&1ull)?FLT_MAX:dl[j];
          bool b1=(d<m1), b2=(d<m2);
          float nm2=b1?m1:(b2?d:m2); int nj2=b1?j1:(b2?j:j2);
          float nm1=b1?d:m1;         int nj1=b1?j:j1;
          m1=nm1;j1=nj1;m2=nm2;j2=nj2;
        }
      }
    }
  }
}

// ---------------------------------------------------------------- GEO fused (GEMM-style)
// (unchanged from round 9)
__global__ __launch_bounds__(256) void geo_kernel(
    const float* __restrict__ xyz, const float* __restrict__ outc,
    const u16t* __restrict__ gidx16, const float* __restrict__ W1,
    const float* __restrict__ Wout, float* __restrict__ xout)
{
  __shared__ float smem[160*33 + 64*128 + 32];
  float (*Es)[33]  = (float(*)[33])smem;
  float (*Hs)[33]  = (float(*)[33])smem;
  float (*Ws)[128] = (float(*)[128])(smem + 160*33);
  float* ssv = smem + 160*33 + 64*128;

  const int t=threadIdx.x;
  const int g0=blockIdx.x*32;
  for (int p=t; p<1024; p+=256){
    int g=p>>5, kk=p&31;
    int gg=g0+g, b=gg>>10;
    int idx=gidx16[gg*K_+kk];
    const float* pt = xyz + ((size_t)b*N_+(size_t)idx)*3;
    const float* cc = outc + (size_t)gg*3;
    float dx=__fsub_rn(pt[0],cc[0]);
    float dy=__fsub_rn(pt[1],cc[1]);
    float dz=__fsub_rn(pt[2],cc[2]);
    float sq=__fadd_rn(__fadd_rn(__fmul_rn(dx,dx),__fmul_rn(dy,dy)),__fmul_rn(dz,dz));
    int r=5*kk;
    Es[r][g]=dx; Es[r+1][g]=dy; Es[r+2][g]=dz;
    Es[r+3][g]=-1.f; Es[r+4][g]=__fmul_rn(-0.5f,sq);
  }
  const int gsub=t>>4, hsub=t&15, h0=hsub*8;
  const int hw=t>>1;
  float acc[2][8];
#pragma unroll
  for (int a=0;a<2;a++)
#pragma unroll
    for (int j=0;j<8;j++) acc[a][j]=0.f;
  __syncthreads();

  for (int c=0;c<3;c++){
    int i0=c*64;
    if (c<2){
      int fw0=(t&1)*32;
      const float* wr = W1 + (size_t)hw*GEO_IN_ + i0 + fw0;
      float4 wv[8];
#pragma unroll
      for (int e=0;e<8;e++) wv[e]=((const float4*)wr)[e];
#pragma unroll
      for (int e=0;e<8;e++){
        Ws[fw0+4*e+0][hw]=wv[e].x;
        Ws[fw0+4*e+1][hw]=wv[e].y;
        Ws[fw0+4*e+2][hw]=wv[e].z;
        Ws[fw0+4*e+3][hw]=wv[e].w;
      }
    } else {
      int fw0=(t&1)*16;
      const float* wr = W1 + (size_t)hw*GEO_IN_ + 128 + fw0;
      float4 wv[4];
#pragma unroll
      for (int e=0;e<4;e++) wv[e]=((const float4*)wr)[e];
#pragma unroll
      for (int e=0;e<4;e++){
        Ws[fw0+4*e+0][hw]=wv[e].x;
        Ws[fw0+4*e+1][hw]=wv[e].y;
        Ws[fw0+4*e+2][hw]=wv[e].z;
        Ws[fw0+4*e+3][hw]=wv[e].w;
      }
    }
    __syncthreads();
    int len=(c==2)?32:64;
    for (int k2=0;k2<len;k2++){
      float x0=Es[i0+k2][2*gsub], x1=Es[i0+k2][2*gsub+1];
      const float* wp=&Ws[k2][h0];
      float4 wa=*(const float4*)wp;
      float4 wb=*(const float4*)(wp+4);
      acc[0][0]=__builtin_fmaf(x0,wa.x,acc[0][0]);
      acc[0][1]=__builtin_fmaf(x0,wa.y,acc[0][1]);
      acc[0][2]=__builtin_fmaf(x0,wa.z,acc[0][2]);
      acc[0][3]=__builtin_fmaf(x0,wa.w,acc[0][3]);
      acc[0][4]=__builtin_fmaf(x0,wb.x,acc[0][4]);
      acc[0][5]=__builtin_fmaf(x0,wb.y,acc[0][5]);
      acc[0][6]=__builtin_fmaf(x0,wb.z,acc[0][6]);
      acc[0][7]=__builtin_fmaf(x0,wb.w,acc[0][7]);
      acc[1][0]=__builtin_fmaf(x1,wa.x,acc[1][0]);
      acc[1][1]=__builtin_fmaf(x1,wa.y,acc[1][1]);
      acc[1][2]=__builtin_fmaf(x1,wa.z,acc[1][2]);
      acc[1][3]=__builtin_fmaf(x1,wa.w,acc[1][3]);
      acc[1][4]=__builtin_fmaf(x1,wb.x,acc[1][4]);
      acc[1][5]=__builtin_fmaf(x1,wb.y,acc[1][5]);
      acc[1][6]=__builtin_fmaf(x1,wb.z,acc[1][6]);
      acc[1][7]=__builtin_fmaf(x1,wb.w,acc[1][7]);
    }
    __syncthreads();
  }
#pragma unroll
  for (int a=0;a<2;a++)
#pragma unroll
    for (int j=0;j<8;j++)
      Hs[h0+j][2*gsub+a]=acc[a][j];
  __syncthreads();
  if (t<32){
    float ss=0.f;
    for (int h=0;h<H_;h++){ float v=Hs[h][t]; ss=__builtin_fmaf(v,v,ss); }
    ssv[t]=__fmul_rn(-0.5f,ss);
  }
#pragma unroll
  for (int a=0;a<2;a++)
#pragma unroll
    for (int j=0;j<8;j++) acc[a][j]=0.f;
  for (int c=0;c<2;c++){
    int i0=c*64;
    int fw0=(t&1)*32;
    const float* wr = Wout + (size_t)hw*GEO_MID_ + i0 + fw0;
    float2 wv2[16];
#pragma unroll
    for (int e=0;e<16;e++) wv2[e]=((const float2*)wr)[e];
    __syncthreads();
#pragma unroll
    for (int e=0;e<16;e++){
      Ws[fw0+2*e+0][hw]=wv2[e].x;
      Ws[fw0+2*e+1][hw]=wv2[e].y;
    }
    __syncthreads();
    for (int k2=0;k2<64;k2++){
      float x0=Hs[i0+k2][2*gsub], x1=Hs[i0+k2][2*gsub+1];
      const float* wp=&Ws[k2][h0];
      float4 wa=*(const float4*)wp;
      float4 wb=*(const float4*)(wp+4);
      acc[0][0]=__builtin_fmaf(x0,wa.x,acc[0][0]);
      acc[0][1]=__builtin_fmaf(x0,wa.y,acc[0][1]);
      acc[0][2]=__builtin_fmaf(x0,wa.z,acc[0][2]);
      acc[0][3]=__builtin_fmaf(x0,wa.w,acc[0][3]);
      acc[0][4]=__builtin_fmaf(x0,wb.x,acc[0][4]);
      acc[0][5]=__builtin_fmaf(x0,wb.y,acc[0][5]);
      acc[0][6]=__builtin_fmaf(x0,wb.z,acc[0][6]);
      acc[0][7]=__builtin_fmaf(x0,wb.w,acc[0][7]);
      acc[1][0]=__builtin_fmaf(x1,wa.x,acc[1][0]);
      acc[1][1]=__builtin_fmaf(x1,wa.y,acc[1][1]);
      acc[1][2]=__builtin_fmaf(x1,wa.z,acc[1][2]);
      acc[1][3]=__builtin_fmaf(x1,wa.w,acc[1][3]);
      acc[1][4]=__builtin_fmaf(x1,wb.x,acc[1][4]);
      acc[1][5]=__builtin_fmaf(x1,wb.y,acc[1][5]);
      acc[1][6]=__builtin_fmaf(x1,wb.z,acc[1][6]);
      acc[1][7]=__builtin_fmaf(x1,wb.w,acc[1][7]);
    }
  }
#pragma unroll
  for (int j=0;j<8;j++){
    int o=h0+j;
    float2 we=*(const float2*)(Wout + (size_t)o*GEO_MID_ + 128);
#pragma unroll
    for (int a=0;a<2;a++){
      float v=acc[a][j];
      v=__builtin_fmaf(-1.f, we.x, v);
      v=__builtin_fmaf(ssv[2*gsub+a], we.y, v);
      xout[(size_t)(g0+2*gsub+a)*256 + o]=v;
    }
  }
}

// ---------------------------------------------------------------- FEAT fused
// (unchanged from round 9 — register double-buffered K-loop)
__global__ __launch_bounds__(256) void feat_kernel(
    const float* __restrict__ feats, const u16t* __restrict__ gidx16,
    const float* __restrict__ W1, const float* __restrict__ b1,
    const float* __restrict__ Wout, const float* __restrict__ bout,
    float* __restrict__ xout)
{
  __shared__ float smem[12800];                      // 51.2 KB
  float (*Xs)[68]  = (float(*)[68])smem;
  float (*Ws)[128] = (float(*)[128])(smem + 64*68);
  float (*Hs)[68]  = (float(*)[68])smem;
  float (*WoS)[128]= (float(*)[128])(smem + 128*68);
  const int t=threadIdx.x;
  const int g0=blockIdx.x*64;
  const int gsub=t>>4;
  const int h0=(t&15)*8;
  const int glx=t>>2, fq=(t&3)*16;
  const int hw=t>>1, fw0=(t&1)*32;
  const int fw1=(t&1)*16;
  const int gld=g0+glx, bld=gld>>10;
  float acc[4][8];
#pragma unroll
  for (int a=0;a<4;a++)
#pragma unroll
    for (int j=0;j<8;j++) acc[a][j]=0.f;

  float4 p[4], wv[8];
  {
    int nidx0 = gidx16[gld*K_+0];
    const float* fr=feats + ((size_t)bld*N_+(size_t)nidx0)*FEAT_ + fq;
#pragma unroll
    for (int e=0;e<4;e++) p[e]=((const float4*)fr)[e];
    const float* wr=W1 + (size_t)hw*FEAT_IN_ + fw0;
#pragma unroll
    for (int e=0;e<8;e++) wv[e]=((const float4*)wr)[e];
  }
  int nidx_n = gidx16[gld*K_+1];

  for (int kk=0;kk<K_;kk++){
    __syncthreads();
#pragma unroll
    for (int e=0;e<4;e++){
      Xs[fq+4*e+0][glx]=p[e].x;
      Xs[fq+4*e+1][glx]=p[e].y;
      Xs[fq+4*e+2][glx]=p[e].z;
      Xs[fq+4*e+3][glx]=p[e].w;
    }
#pragma unroll
    for (int e=0;e<8;e++){
      Ws[fw0+4*e+0][hw]=wv[e].x;
      Ws[fw0+4*e+1][hw]=wv[e].y;
      Ws[fw0+4*e+2][hw]=wv[e].z;
      Ws[fw0+4*e+3][hw]=wv[e].w;
    }
    __syncthreads();
    float4 pn[4], wn[8];
    int nidx_n2=0;
    if (kk+1<K_){
      const float* frn=feats + ((size_t)bld*N_+(size_t)nidx_n)*FEAT_ + fq;
#pragma unroll
      for (int e=0;e<4;e++) pn[e]=((const float4*)frn)[e];
      const float* wrn=W1 + (size_t)hw*FEAT_IN_ + (kk+1)*64 + fw0;
#pragma unroll
      for (int e=0;e<8;e++) wn[e]=((const float4*)wrn)[e];
      if (kk+2<K_) nidx_n2 = gidx16[gld*K_+kk+2];
    }
#pragma unroll 4
    for (int k2=0;k2<64;k2++){
      float4 xv=*(const float4*)&Xs[k2][4*gsub];
      const float* wp=&Ws[k2][h0];
      float4 wa=*(const float4*)wp;
      float4 wb=*(const float4*)(wp+4);
      float xr[4]={xv.x,xv.y,xv.z,xv.w};
      float wf[8]={wa.x,wa.y,wa.z,wa.w,wb.x,wb.y,wb.z,wb.w};
#pragma unroll
      for (int a=0;a<4;a++)
#pragma unroll
        for (int j=0;j<8;j++)
          acc[a][j]=__builtin_fmaf(xr[a],wf[j],acc[a][j]);
    }
    if (kk+1<K_){
#pragma unroll
      for (int e=0;e<4;e++) p[e]=pn[e];
#pragma unroll
      for (int e=0;e<8;e++) wv[e]=wn[e];
      nidx_n=nidx_n2;
    }
  }
  __syncthreads();
#pragma unroll
  for (int j=0;j<8;j++){
    float bv=b1[h0+j];
#pragma unroll
    for (int a=0;a<4;a++)
      Hs[h0+j][4*gsub+a]=fmaxf(__fadd_rn(acc[a][j],bv),0.f);
  }
  float ac2[4][8];
#pragma unroll
  for (int a=0;a<4;a++)
#pragma unroll
    for (int j=0;j<8;j++) ac2[a][j]=0.f;
  for (int c=0;c<4;c++){
    const float* wr2=Wout + (size_t)hw*H_ + c*32 + fw1;
    float4 w2[4];
#pragma unroll
    for (int e=0;e<4;e++) w2[e]=((const float4*)wr2)[e];
    __syncthreads();
#pragma unroll
    for (int e=0;e<4;e++){
      WoS[fw1+4*e+0][hw]=w2[e].x;
      WoS[fw1+4*e+1][hw]=w2[e].y;
      WoS[fw1+4*e+2][hw]=w2[e].z;
      WoS[fw1+4*e+3][hw]=w2[e].w;
    }
    __syncthreads();
#pragma unroll 4
    for (int k2=0;k2<32;k2++){
      float4 xv=*(const float4*)&Hs[c*32+k2][4*gsub];
      const float* wp=&WoS[k2][h0];
      float4 wa=*(const float4*)wp;
      float4 wb=*(const float4*)(wp+4);
      float xr[4]={xv.x,xv.y,xv.z,xv.w};
      float wf[8]={wa.x,wa.y,wa.z,wa.w,wb.x,wb.y,wb.z,wb.w};
#pragma unroll
      for (int a=0;a<4;a++)
#pragma unroll
        for (int j=0;j<8;j++)
          ac2[a][j]=__builtin_fmaf(xr[a],wf[j],ac2[a][j]);
    }
  }
#pragma unroll
  for (int j=0;j<8;j++){
    float bv=bout[h0+j];
#pragma unroll
    for (int a=0;a<4;a++)
      xout[(size_t)(g0+4*gsub+a)*256+128+h0+j]=__fadd_rn(ac2[a][j],bv);
  }
}

// ----------------------------------------------------------------
extern "C" void kernel_launch(void* const* d_in, const int* in_sizes, int n_in,
                              void* d_out, int out_size, void* d_ws, size_t ws_size,
                              hipStream_t stream) {
  const float* xyz  =(const float*)d_in[0];
  const float* feats=(const float*)d_in[1];
  const float* gW1  =(const float*)d_in[2];
  const float* gWout=(const float*)d_in[3];
  const float* fW1  =(const float*)d_in[4];
  const float* fb1  =(const float*)d_in[5];
  const float* fWout=(const float*)d_in[6];
  const float* fbout=(const float*)d_in[7];
  float* out=(float*)d_out;

  u16t* gidx16=(u16t*)d_ws;          // 1 MB
  float* xout = out + (size_t)B_*M_*3;

  fps_kernel <<<dim3(B_),          dim3(64),  0, stream>>>(xyz, out);
  knn_kernel <<<dim3((B_*M_)/4),   dim3(256), 0, stream>>>(xyz, out, gidx16);
  geo_kernel <<<dim3((B_*M_)/32),  dim3(256), 0, stream>>>(xyz, out, gidx16, gW1, gWout, xout);
  feat_kernel<<<dim3((B_*M_)/64),  dim3(256), 0, stream>>>(feats, gidx16, fW1, fb1, fWout, fbout, xout);
}